// Round 3
// baseline (3068.296 us; speedup 1.0000x reference)
//
#include <hip/hip_runtime.h>
#include <hip/hip_bf16.h>

#define N_NODES 50000
#define DIM 64
#define N_EDGES 800000

__device__ __forceinline__ float silu_f(float x) {
    return x * __builtin_amdgcn_rcpf(1.0f + __expf(-x));
}

// ---------------- Kernel 0: hp = h + h_init; zero accumulators; detect eidx dtype ----------------
__global__ void k_init(const float* __restrict__ h, const float* __restrict__ h_init,
                       float* __restrict__ hp, float* __restrict__ agg,
                       float* __restrict__ posw, float* __restrict__ deg,
                       const void* __restrict__ eidx, int* __restrict__ flag) {
    int i = blockIdx.x * blockDim.x + threadIdx.x;
    int stride = gridDim.x * blockDim.x;
    for (int idx = i; idx < N_NODES * DIM; idx += stride) {
        hp[idx]  = h[idx] + h_init[idx];
        agg[idx] = 0.0f;
    }
    for (int idx = i; idx < N_NODES * 2; idx += stride) posw[idx] = 0.0f;
    for (int idx = i; idx < N_NODES; idx += stride) deg[idx] = 0.0f;

    // dtype probe: int64 little-endian => hi words (odd int32 positions) all 0
    // (node ids < 50000); int32 => odd positions are random node ids (P(all 0) ~ 0).
    if (blockIdx.x == 0 && threadIdx.x == 0) {
        const int* e32 = (const int*)eidx;
        int f = 1;
        for (int k = 0; k < 64; ++k) {
            if (e32[2 * k + 1] != 0) { f = 0; break; }
        }
        flag[0] = f;
    }
}

// ---------------- Kernel 1: per-edge message MLP + scatter ----------------
// thread = edge. Weights in LDS (wave-uniform broadcast reads).
// sB layout: [0..63]=b_msg1, [64..127]=b_msg2, [128..191]=b_pos1, [192..255]=W_pos2, [256]=b_pos2
__global__ __launch_bounds__(512, 2)
void k_edge(const float* __restrict__ hp, const float* __restrict__ pos,
            const void* __restrict__ eidx, const int* __restrict__ flag,
            const float* __restrict__ Wm1, const float* __restrict__ bm1,
            const float* __restrict__ Wm2, const float* __restrict__ bm2,
            const float* __restrict__ Wp1, const float* __restrict__ bp1,
            const float* __restrict__ Wp2, const float* __restrict__ bp2,
            float* __restrict__ agg, float* __restrict__ posw, float* __restrict__ deg)
{
    __shared__ float sWm1[129 * 64];   // [k][d], k=0..63 h[dst], 64..127 h[src], 128 d2
    __shared__ float sWm2t[64 * 64];   // transposed: [d][k]
    __shared__ float sWp1[64 * 64];    // [k][d]
    __shared__ float sB[257];

    for (int i = threadIdx.x; i < 129 * 64; i += 512) sWm1[i] = Wm1[i];
    for (int i = threadIdx.x; i < 64 * 64; i += 512) {
        int k = i >> 6, d = i & 63;
        sWm2t[d * 64 + k] = Wm2[i];
        sWp1[i] = Wp1[i];
    }
    if (threadIdx.x < 64) {
        sB[threadIdx.x]       = bm1[threadIdx.x];
        sB[64 + threadIdx.x]  = bm2[threadIdx.x];
        sB[128 + threadIdx.x] = bp1[threadIdx.x];
        sB[192 + threadIdx.x] = Wp2[threadIdx.x];
    }
    if (threadIdx.x == 0) sB[256] = bp2[0];
    __syncthreads();

    const float4* W1v  = reinterpret_cast<const float4*>(sWm1);
    const float4* W2tv = reinterpret_cast<const float4*>(sWm2t);
    const float4* Wp1v = reinterpret_cast<const float4*>(sWp1);

    const int is64 = flag[0];
    const int* e32 = (const int*)eidx;
    const long long* e64 = (const long long*)eidx;

    int tid = blockIdx.x * blockDim.x + threadIdx.x;
    int gstride = gridDim.x * blockDim.x;

    for (int e = tid; e < N_EDGES; e += gstride) {
        int src, dst;
        if (is64) {
            src = (int)e64[e];
            dst = (int)e64[N_EDGES + e];
        } else {
            src = e32[e];
            dst = e32[N_EDGES + e];
        }

        float2 pd = *reinterpret_cast<const float2*>(pos + (size_t)dst * 2);
        float2 ps = *reinterpret_cast<const float2*>(pos + (size_t)src * 2);
        float relx = pd.x - ps.x;
        float rely = pd.y - ps.y;
        float d2 = relx * relx + rely * rely;

        const float4* rowd = reinterpret_cast<const float4*>(hp + (size_t)dst * DIM);
        const float4* rows = reinterpret_cast<const float4*>(hp + (size_t)src * DIM);

        // ---- layer 1: t1 = silu(m_in @ W_msg1 + b_msg1) ----
        float t1[64];
        #pragma unroll
        for (int d = 0; d < 64; ++d) t1[d] = sB[d];

        for (int kc = 0; kc < 16; ++kc) {
            float4 ad = rowd[kc];
            float4 as = rows[kc];
            #pragma unroll
            for (int j = 0; j < 4; ++j) {
                float aj = (j == 0) ? ad.x : (j == 1) ? ad.y : (j == 2) ? ad.z : ad.w;
                float bj = (j == 0) ? as.x : (j == 1) ? as.y : (j == 2) ? as.z : as.w;
                int k = kc * 4 + j;
                #pragma unroll
                for (int dv = 0; dv < 16; ++dv) {
                    float4 w1 = W1v[k * 16 + dv];
                    t1[dv * 4 + 0] = fmaf(aj, w1.x, t1[dv * 4 + 0]);
                    t1[dv * 4 + 1] = fmaf(aj, w1.y, t1[dv * 4 + 1]);
                    t1[dv * 4 + 2] = fmaf(aj, w1.z, t1[dv * 4 + 2]);
                    t1[dv * 4 + 3] = fmaf(aj, w1.w, t1[dv * 4 + 3]);
                    float4 w2 = W1v[(64 + k) * 16 + dv];
                    t1[dv * 4 + 0] = fmaf(bj, w2.x, t1[dv * 4 + 0]);
                    t1[dv * 4 + 1] = fmaf(bj, w2.y, t1[dv * 4 + 1]);
                    t1[dv * 4 + 2] = fmaf(bj, w2.z, t1[dv * 4 + 2]);
                    t1[dv * 4 + 3] = fmaf(bj, w2.w, t1[dv * 4 + 3]);
                }
            }
        }
        // d2 row (k = 128) + silu
        #pragma unroll
        for (int dv = 0; dv < 16; ++dv) {
            float4 w1 = W1v[128 * 16 + dv];
            t1[dv * 4 + 0] = silu_f(fmaf(d2, w1.x, t1[dv * 4 + 0]));
            t1[dv * 4 + 1] = silu_f(fmaf(d2, w1.y, t1[dv * 4 + 1]));
            t1[dv * 4 + 2] = silu_f(fmaf(d2, w1.z, t1[dv * 4 + 2]));
            t1[dv * 4 + 3] = silu_f(fmaf(d2, w1.w, t1[dv * 4 + 3]));
        }

        // ---- layer 2 (d-outer) fused with agg-scatter and phi_x layer 1 ----
        float acc3[64];
        #pragma unroll
        for (int d = 0; d < 64; ++d) acc3[d] = sB[128 + d];

        for (int kd = 0; kd < 64; ++kd) {
            float s = sB[64 + kd];
            #pragma unroll
            for (int kv = 0; kv < 16; ++kv) {
                float4 wv = W2tv[kd * 16 + kv];
                s = fmaf(t1[kv * 4 + 0], wv.x, s);
                s = fmaf(t1[kv * 4 + 1], wv.y, s);
                s = fmaf(t1[kv * 4 + 2], wv.z, s);
                s = fmaf(t1[kv * 4 + 3], wv.w, s);
            }
            float mk = silu_f(s);                       // m[kd]
            atomicAdd(&agg[(size_t)dst * DIM + kd], mk);
            #pragma unroll
            for (int dv = 0; dv < 16; ++dv) {
                float4 w = Wp1v[kd * 16 + dv];
                acc3[dv * 4 + 0] = fmaf(mk, w.x, acc3[dv * 4 + 0]);
                acc3[dv * 4 + 1] = fmaf(mk, w.y, acc3[dv * 4 + 1]);
                acc3[dv * 4 + 2] = fmaf(mk, w.z, acc3[dv * 4 + 2]);
                acc3[dv * 4 + 3] = fmaf(mk, w.w, acc3[dv * 4 + 3]);
            }
        }

        // ---- phi_x layer 2: w = silu(acc3) . W_pos2 + b_pos2 ----
        float wgt = sB[256];
        #pragma unroll
        for (int d = 0; d < 64; ++d) wgt = fmaf(silu_f(acc3[d]), sB[192 + d], wgt);

        atomicAdd(&posw[(size_t)dst * 2 + 0], relx * wgt);
        atomicAdd(&posw[(size_t)dst * 2 + 1], rely * wgt);
        atomicAdd(&deg[dst], 1.0f);
    }
}

// ---------------- Kernel 2: node MLP + outputs (FLOAT32 out) ----------------
__global__ __launch_bounds__(512, 2)
void k_node(const float* __restrict__ hp, const float* __restrict__ pos,
            const float* __restrict__ agg, const float* __restrict__ posw,
            const float* __restrict__ deg,
            const float* __restrict__ Wh1, const float* __restrict__ bh1,
            const float* __restrict__ Wh2, const float* __restrict__ bh2,
            float* __restrict__ out)
{
    __shared__ float sW1[128 * 64];   // [k][d]
    __shared__ float sW2t[64 * 64];   // transposed [d][k]
    __shared__ float sB1[64];
    __shared__ float sB2[64];

    for (int i = threadIdx.x; i < 128 * 64; i += 512) sW1[i] = Wh1[i];
    for (int i = threadIdx.x; i < 64 * 64; i += 512) {
        int k = i >> 6, d = i & 63;
        sW2t[d * 64 + k] = Wh2[i];
    }
    if (threadIdx.x < 64) {
        sB1[threadIdx.x] = bh1[threadIdx.x];
        sB2[threadIdx.x] = bh2[threadIdx.x];
    }
    __syncthreads();

    const float4* W1v  = reinterpret_cast<const float4*>(sW1);
    const float4* W2tv = reinterpret_cast<const float4*>(sW2t);

    int tid = blockIdx.x * blockDim.x + threadIdx.x;
    int gstride = gridDim.x * blockDim.x;

    for (int n = tid; n < N_NODES; n += gstride) {
        const float4* rh = reinterpret_cast<const float4*>(hp + (size_t)n * DIM);
        const float4* ra = reinterpret_cast<const float4*>(agg + (size_t)n * DIM);

        float t[64];
        #pragma unroll
        for (int d = 0; d < 64; ++d) t[d] = sB1[d];

        for (int kc = 0; kc < 16; ++kc) {
            float4 ah = rh[kc];
            float4 aa = ra[kc];
            #pragma unroll
            for (int j = 0; j < 4; ++j) {
                float hj = (j == 0) ? ah.x : (j == 1) ? ah.y : (j == 2) ? ah.z : ah.w;
                float aj = (j == 0) ? aa.x : (j == 1) ? aa.y : (j == 2) ? aa.z : aa.w;
                int k = kc * 4 + j;
                #pragma unroll
                for (int dv = 0; dv < 16; ++dv) {
                    float4 w1 = W1v[k * 16 + dv];
                    t[dv * 4 + 0] = fmaf(hj, w1.x, t[dv * 4 + 0]);
                    t[dv * 4 + 1] = fmaf(hj, w1.y, t[dv * 4 + 1]);
                    t[dv * 4 + 2] = fmaf(hj, w1.z, t[dv * 4 + 2]);
                    t[dv * 4 + 3] = fmaf(hj, w1.w, t[dv * 4 + 3]);
                    float4 w2 = W1v[(64 + k) * 16 + dv];
                    t[dv * 4 + 0] = fmaf(aj, w2.x, t[dv * 4 + 0]);
                    t[dv * 4 + 1] = fmaf(aj, w2.y, t[dv * 4 + 1]);
                    t[dv * 4 + 2] = fmaf(aj, w2.z, t[dv * 4 + 2]);
                    t[dv * 4 + 3] = fmaf(aj, w2.w, t[dv * 4 + 3]);
                }
            }
        }
        #pragma unroll
        for (int d = 0; d < 64; ++d) t[d] = silu_f(t[d]);

        // layer 2 (no activation): out_h = hp + t @ W_h2 + b_h2
        for (int kd = 0; kd < 64; ++kd) {
            float s = sB2[kd];
            #pragma unroll
            for (int kv = 0; kv < 16; ++kv) {
                float4 wv = W2tv[kd * 16 + kv];
                s = fmaf(t[kv * 4 + 0], wv.x, s);
                s = fmaf(t[kv * 4 + 1], wv.y, s);
                s = fmaf(t[kv * 4 + 2], wv.z, s);
                s = fmaf(t[kv * 4 + 3], wv.w, s);
            }
            out[(size_t)n * DIM + kd] = hp[(size_t)n * DIM + kd] + s;
        }

        // pos output
        float dg = fmaxf(deg[n], 1.0f);
        float inv = __builtin_amdgcn_rcpf(dg);
        float2 po = *reinterpret_cast<const float2*>(pos + (size_t)n * 2);
        float2 pw = *reinterpret_cast<const float2*>(posw + (size_t)n * 2);
        float2 res;
        res.x = po.x + pw.x * inv;
        res.y = po.y + pw.y * inv;
        *reinterpret_cast<float2*>(out + (size_t)N_NODES * DIM + (size_t)n * 2) = res;
    }
}

extern "C" void kernel_launch(void* const* d_in, const int* in_sizes, int n_in,
                              void* d_out, int out_size, void* d_ws, size_t ws_size,
                              hipStream_t stream) {
    const float* h      = (const float*)d_in[0];
    const float* pos    = (const float*)d_in[1];
    const float* h_init = (const float*)d_in[2];
    const float* Wm1    = (const float*)d_in[3];
    const float* bm1    = (const float*)d_in[4];
    const float* Wm2    = (const float*)d_in[5];
    const float* bm2    = (const float*)d_in[6];
    const float* Wp1    = (const float*)d_in[7];
    const float* bp1    = (const float*)d_in[8];
    const float* Wp2    = (const float*)d_in[9];
    const float* bp2    = (const float*)d_in[10];
    const float* Wh1    = (const float*)d_in[11];
    const float* bh1    = (const float*)d_in[12];
    const float* Wh2    = (const float*)d_in[13];
    const float* bh2    = (const float*)d_in[14];
    const void*  eidx   = (const void*)d_in[15];
    float* out = (float*)d_out;

    float* ws   = (float*)d_ws;
    float* hp   = ws;                               // N*64
    float* agg  = ws + (size_t)N_NODES * DIM;       // N*64
    float* posw = agg + (size_t)N_NODES * DIM;      // N*2
    float* deg  = posw + (size_t)N_NODES * 2;       // N
    int*   flag = (int*)(deg + N_NODES);            // 1

    k_init<<<12500, 256, 0, stream>>>(h, h_init, hp, agg, posw, deg, eidx, flag);
    k_edge<<<1563, 512, 0, stream>>>(hp, pos, eidx, flag, Wm1, bm1, Wm2, bm2,
                                     Wp1, bp1, Wp2, bp2, agg, posw, deg);
    k_node<<<98, 512, 0, stream>>>(hp, pos, agg, posw, deg, Wh1, bh1, Wh2, bh2, out);
}

// Round 4
// 392.733 us; speedup vs baseline: 7.8127x; 7.8127x over previous
//
#include <hip/hip_runtime.h>
#include <hip/hip_bf16.h>

#define N_NODES 50000
#define DIM 64
#define N_EDGES 800000
#define NTILES (N_EDGES / 16)

typedef short short8 __attribute__((ext_vector_type(8)));
typedef float f32x4 __attribute__((ext_vector_type(4)));

__device__ __forceinline__ float silu_f(float x) {
    return x * __builtin_amdgcn_rcpf(1.0f + __expf(-x));
}
// f32 -> bf16 round-to-nearest-even
__device__ __forceinline__ short f2bf(float f) {
    unsigned u = __builtin_bit_cast(unsigned, f);
    u += 0x7FFFu + ((u >> 16) & 1u);
    return (short)(u >> 16);
}

// ---------------- Kernel 0: hp = h + h_init; zero accumulators; detect eidx dtype ----------------
__global__ void k_init(const float* __restrict__ h, const float* __restrict__ h_init,
                       float* __restrict__ hp, float* __restrict__ agg,
                       float* __restrict__ posw, float* __restrict__ deg,
                       const void* __restrict__ eidx, int* __restrict__ flag) {
    int i = blockIdx.x * blockDim.x + threadIdx.x;
    int stride = gridDim.x * blockDim.x;
    for (int idx = i; idx < N_NODES * DIM; idx += stride) {
        hp[idx]  = h[idx] + h_init[idx];
        agg[idx] = 0.0f;
    }
    for (int idx = i; idx < N_NODES * 2; idx += stride) posw[idx] = 0.0f;
    for (int idx = i; idx < N_NODES; idx += stride) deg[idx] = 0.0f;

    if (blockIdx.x == 0 && threadIdx.x == 0) {
        const int* e32 = (const int*)eidx;
        int f = 1;
        for (int k = 0; k < 64; ++k) {
            if (e32[2 * k + 1] != 0) { f = 0; break; }
        }
        flag[0] = f;
    }
}

// ---------------- Kernel 1: MFMA edge pipeline ----------------
// wave = 16-edge tile. Weights pre-packed in B-fragment layout (bf16) in LDS.
// mfma_f32_16x16x32_bf16 layouts: A: row=lane&15, k=8*(lane>>4)+j
//                                 B: col=lane&15, k=8*(lane>>4)+j
//                                 C/D: col=lane&15, row=(lane>>4)*4+reg   [guide-verified]
__global__ __launch_bounds__(512)
void k_edge(const float* __restrict__ hp, const float* __restrict__ pos,
            const void* __restrict__ eidx, const int* __restrict__ flag,
            const float* __restrict__ Wm1, const float* __restrict__ bm1,
            const float* __restrict__ Wm2, const float* __restrict__ bm2,
            const float* __restrict__ Wp1, const float* __restrict__ bp1,
            const float* __restrict__ Wp2, const float* __restrict__ bp2,
            float* __restrict__ agg, float* __restrict__ posw, float* __restrict__ deg)
{
    __shared__ short sW1[10240];     // 5 kk x 4 nt x 64 lanes x 8 (K=160 padded, rows>=129 zero)
    __shared__ short sW2[4096];      // 2 kk x 4 nt x 64 x 8
    __shared__ short sWp[4096];      // 2 kk x 4 nt x 64 x 8
    __shared__ float sB[260];        // 0..63 bm1 | 64..127 bm2 | 128..191 bp1 | 192..255 Wp2 | 256 bp2
    __shared__ short sT[8][1024];    // per-wave 16x64 bf16 bounce tile (XOR-swizzled)

    // ---- stage weights in fragment order ----
    for (int i = threadIdx.x; i < 10240; i += 512) {
        int j = i & 7, lane = (i >> 3) & 63, nt = (i >> 9) & 3, kk = i >> 11;
        int k = kk * 32 + ((lane >> 4) << 3) + j;
        int n = (nt << 4) + (lane & 15);
        sW1[i] = (k < 129) ? f2bf(Wm1[k * 64 + n]) : (short)0;
    }
    for (int i = threadIdx.x; i < 4096; i += 512) {
        int j = i & 7, lane = (i >> 3) & 63, nt = (i >> 9) & 3, kk = i >> 11;
        int k = kk * 32 + ((lane >> 4) << 3) + j;
        int n = (nt << 4) + (lane & 15);
        sW2[i] = f2bf(Wm2[k * 64 + n]);
        sWp[i] = f2bf(Wp1[k * 64 + n]);
    }
    if (threadIdx.x < 64) {
        sB[threadIdx.x]       = bm1[threadIdx.x];
        sB[64 + threadIdx.x]  = bm2[threadIdx.x];
        sB[128 + threadIdx.x] = bp1[threadIdx.x];
        sB[192 + threadIdx.x] = Wp2[threadIdx.x];
    }
    if (threadIdx.x == 0) sB[256] = bp2[0];
    __syncthreads();

    const int lane = threadIdx.x & 63;
    const int wv   = threadIdx.x >> 6;
    const int g    = lane >> 4;
    const int c    = lane & 15;
    short* tile = &sT[wv][0];

    const int is64 = flag[0];
    const int* e32 = (const int*)eidx;
    const long long* e64 = (const long long*)eidx;

    float bi1[4], bi2[4], bip[4], wp2r[4];
    #pragma unroll
    for (int nt = 0; nt < 4; ++nt) {
        bi1[nt]  = sB[nt * 16 + c];
        bi2[nt]  = sB[64 + nt * 16 + c];
        bip[nt]  = sB[128 + nt * 16 + c];
        wp2r[nt] = sB[192 + nt * 16 + c];
    }
    const float bp2v = sB[256];

    const int gw = blockIdx.x * 8 + wv;
    const int nw = gridDim.x * 8;

    for (int t = gw; t < NTILES; t += nw) {
        const int e = t * 16 + c;           // this lane gathers edge-local row c
        int src, dst;
        if (is64) { src = (int)e64[e]; dst = (int)e64[N_EDGES + e]; }
        else      { src = e32[e];      dst = e32[N_EDGES + e]; }

        float2 pd = *(const float2*)(pos + (size_t)dst * 2);
        float2 ps = *(const float2*)(pos + (size_t)src * 2);
        float relx = pd.x - ps.x, rely = pd.y - ps.y;
        float d2 = relx * relx + rely * rely;

        const float* rowd = hp + (size_t)dst * 64 + g * 8;
        const float* rows = hp + (size_t)src * 64 + g * 8;

        // ---- layer 1: [16 x 160] @ [160 x 64] ----
        f32x4 acc[4];
        #pragma unroll
        for (int nt = 0; nt < 4; ++nt) acc[nt] = f32x4{0.f, 0.f, 0.f, 0.f};

        #pragma unroll
        for (int kk = 0; kk < 4; ++kk) {
            const float* p = (kk < 2) ? (rowd + kk * 32) : (rows + (kk - 2) * 32);
            float4 v0 = *(const float4*)p;
            float4 v1 = *(const float4*)(p + 4);
            short8 a;
            a[0] = f2bf(v0.x); a[1] = f2bf(v0.y); a[2] = f2bf(v0.z); a[3] = f2bf(v0.w);
            a[4] = f2bf(v1.x); a[5] = f2bf(v1.y); a[6] = f2bf(v1.z); a[7] = f2bf(v1.w);
            #pragma unroll
            for (int nt = 0; nt < 4; ++nt) {
                short8 b = *(const short8*)&sW1[(((kk << 2) + nt) << 9) + (lane << 3)];
                acc[nt] = __builtin_amdgcn_mfma_f32_16x16x32_bf16(a, b, acc[nt], 0, 0, 0);
            }
        }
        {   // kk = 4: k=128 is d2, 129..159 zero
            short8 a = {0, 0, 0, 0, 0, 0, 0, 0};
            if (g == 0) a[0] = f2bf(d2);
            #pragma unroll
            for (int nt = 0; nt < 4; ++nt) {
                short8 b = *(const short8*)&sW1[((16 + nt) << 9) + (lane << 3)];
                acc[nt] = __builtin_amdgcn_mfma_f32_16x16x32_bf16(a, b, acc[nt], 0, 0, 0);
            }
        }
        // bias + silu -> t1 tile (bf16, XOR swizzle)
        #pragma unroll
        for (int nt = 0; nt < 4; ++nt) {
            #pragma unroll
            for (int r = 0; r < 4; ++r) {
                float v = silu_f(acc[nt][r] + bi1[nt]);
                int row = g * 4 + r;
                int idx = ((row << 6) + (nt << 4) + c) ^ ((row & 7) << 3);
                tile[idx] = f2bf(v);
            }
        }
        asm volatile("s_waitcnt lgkmcnt(0)" ::: "memory");
        __builtin_amdgcn_sched_barrier(0);

        // ---- layer 2: t1[16x64] @ W2[64x64] ----
        short8 a20, a21;
        {
            int row = c;
            int b0 = ((row << 6) + (g << 3)) ^ ((row & 7) << 3);
            int b1 = ((row << 6) + 32 + (g << 3)) ^ ((row & 7) << 3);
            a20 = *(const short8*)&tile[b0];
            a21 = *(const short8*)&tile[b1];
        }
        f32x4 acc2[4];
        #pragma unroll
        for (int nt = 0; nt < 4; ++nt) acc2[nt] = f32x4{0.f, 0.f, 0.f, 0.f};
        #pragma unroll
        for (int nt = 0; nt < 4; ++nt) {
            short8 b0 = *(const short8*)&sW2[(nt << 9) + (lane << 3)];
            short8 b1 = *(const short8*)&sW2[((4 + nt) << 9) + (lane << 3)];
            acc2[nt] = __builtin_amdgcn_mfma_f32_16x16x32_bf16(a20, b0, acc2[nt], 0, 0, 0);
            acc2[nt] = __builtin_amdgcn_mfma_f32_16x16x32_bf16(a21, b1, acc2[nt], 0, 0, 0);
        }
        float mv[4][4];
        #pragma unroll
        for (int nt = 0; nt < 4; ++nt) {
            #pragma unroll
            for (int r = 0; r < 4; ++r) mv[nt][r] = silu_f(acc2[nt][r] + bi2[nt]);
        }
        // write m tile for pos1 A-frags (t1 reads already consumed)
        asm volatile("s_waitcnt lgkmcnt(0)" ::: "memory");
        __builtin_amdgcn_sched_barrier(0);
        #pragma unroll
        for (int nt = 0; nt < 4; ++nt) {
            #pragma unroll
            for (int r = 0; r < 4; ++r) {
                int row = g * 4 + r;
                int idx = ((row << 6) + (nt << 4) + c) ^ ((row & 7) << 3);
                tile[idx] = f2bf(mv[nt][r]);
            }
        }
        // agg scatter: 16 contiguous lanes per instruction (64B bursts)
        #pragma unroll
        for (int r = 0; r < 4; ++r) {
            int q = g * 4 + r;
            int dstr = __shfl(dst, q, 64);
            float* basea = agg + (size_t)dstr * 64 + c;
            #pragma unroll
            for (int nt = 0; nt < 4; ++nt)
                atomicAdd(basea + nt * 16, mv[nt][r]);
        }
        asm volatile("s_waitcnt lgkmcnt(0)" ::: "memory");
        __builtin_amdgcn_sched_barrier(0);

        // ---- pos1: m[16x64] @ Wp1[64x64] ----
        short8 ap0, ap1;
        {
            int row = c;
            int b0 = ((row << 6) + (g << 3)) ^ ((row & 7) << 3);
            int b1 = ((row << 6) + 32 + (g << 3)) ^ ((row & 7) << 3);
            ap0 = *(const short8*)&tile[b0];
            ap1 = *(const short8*)&tile[b1];
        }
        f32x4 acc3[4];
        #pragma unroll
        for (int nt = 0; nt < 4; ++nt) acc3[nt] = f32x4{0.f, 0.f, 0.f, 0.f};
        #pragma unroll
        for (int nt = 0; nt < 4; ++nt) {
            short8 b0 = *(const short8*)&sWp[(nt << 9) + (lane << 3)];
            short8 b1 = *(const short8*)&sWp[((4 + nt) << 9) + (lane << 3)];
            acc3[nt] = __builtin_amdgcn_mfma_f32_16x16x32_bf16(ap0, b0, acc3[nt], 0, 0, 0);
            acc3[nt] = __builtin_amdgcn_mfma_f32_16x16x32_bf16(ap1, b1, acc3[nt], 0, 0, 0);
        }
        // ---- pos2 + scatter ----
        #pragma unroll
        for (int r = 0; r < 4; ++r) {
            float part = 0.f;
            #pragma unroll
            for (int nt = 0; nt < 4; ++nt)
                part = fmaf(silu_f(acc3[nt][r] + bip[nt]), wp2r[nt], part);
            part += __shfl_xor(part, 1, 64);
            part += __shfl_xor(part, 2, 64);
            part += __shfl_xor(part, 4, 64);
            part += __shfl_xor(part, 8, 64);
            float w = part + bp2v;
            int q = g * 4 + r;
            int dstr = __shfl(dst, q, 64);
            float rx = __shfl(relx, q, 64);
            float ry = __shfl(rely, q, 64);
            if (c == 0)      atomicAdd(posw + (size_t)dstr * 2 + 0, rx * w);
            else if (c == 1) atomicAdd(posw + (size_t)dstr * 2 + 1, ry * w);
            else if (c == 2) atomicAdd(deg + dstr, 1.0f);
        }
    }
}

// ---------------- Kernel 2: node MLP + outputs (f32 out) ----------------
__global__ __launch_bounds__(512, 2)
void k_node(const float* __restrict__ hp, const float* __restrict__ pos,
            const float* __restrict__ agg, const float* __restrict__ posw,
            const float* __restrict__ deg,
            const float* __restrict__ Wh1, const float* __restrict__ bh1,
            const float* __restrict__ Wh2, const float* __restrict__ bh2,
            float* __restrict__ out)
{
    __shared__ float sW1[128 * 64];
    __shared__ float sW2t[64 * 64];
    __shared__ float sB1[64];
    __shared__ float sB2[64];

    for (int i = threadIdx.x; i < 128 * 64; i += 512) sW1[i] = Wh1[i];
    for (int i = threadIdx.x; i < 64 * 64; i += 512) {
        int k = i >> 6, d = i & 63;
        sW2t[d * 64 + k] = Wh2[i];
    }
    if (threadIdx.x < 64) {
        sB1[threadIdx.x] = bh1[threadIdx.x];
        sB2[threadIdx.x] = bh2[threadIdx.x];
    }
    __syncthreads();

    const float4* W1v  = reinterpret_cast<const float4*>(sW1);
    const float4* W2tv = reinterpret_cast<const float4*>(sW2t);

    int tid = blockIdx.x * blockDim.x + threadIdx.x;
    int gstride = gridDim.x * blockDim.x;

    for (int n = tid; n < N_NODES; n += gstride) {
        const float4* rh = reinterpret_cast<const float4*>(hp + (size_t)n * DIM);
        const float4* ra = reinterpret_cast<const float4*>(agg + (size_t)n * DIM);

        float t[64];
        #pragma unroll
        for (int d = 0; d < 64; ++d) t[d] = sB1[d];

        for (int kc = 0; kc < 16; ++kc) {
            float4 ah = rh[kc];
            float4 aa = ra[kc];
            #pragma unroll
            for (int j = 0; j < 4; ++j) {
                float hj = (j == 0) ? ah.x : (j == 1) ? ah.y : (j == 2) ? ah.z : ah.w;
                float aj = (j == 0) ? aa.x : (j == 1) ? aa.y : (j == 2) ? aa.z : aa.w;
                int k = kc * 4 + j;
                #pragma unroll
                for (int dv = 0; dv < 16; ++dv) {
                    float4 w1 = W1v[k * 16 + dv];
                    t[dv * 4 + 0] = fmaf(hj, w1.x, t[dv * 4 + 0]);
                    t[dv * 4 + 1] = fmaf(hj, w1.y, t[dv * 4 + 1]);
                    t[dv * 4 + 2] = fmaf(hj, w1.z, t[dv * 4 + 2]);
                    t[dv * 4 + 3] = fmaf(hj, w1.w, t[dv * 4 + 3]);
                    float4 w2 = W1v[(64 + k) * 16 + dv];
                    t[dv * 4 + 0] = fmaf(aj, w2.x, t[dv * 4 + 0]);
                    t[dv * 4 + 1] = fmaf(aj, w2.y, t[dv * 4 + 1]);
                    t[dv * 4 + 2] = fmaf(aj, w2.z, t[dv * 4 + 2]);
                    t[dv * 4 + 3] = fmaf(aj, w2.w, t[dv * 4 + 3]);
                }
            }
        }
        #pragma unroll
        for (int d = 0; d < 64; ++d) t[d] = silu_f(t[d]);

        for (int kd = 0; kd < 64; ++kd) {
            float s = sB2[kd];
            #pragma unroll
            for (int kv = 0; kv < 16; ++kv) {
                float4 wv = W2tv[kd * 16 + kv];
                s = fmaf(t[kv * 4 + 0], wv.x, s);
                s = fmaf(t[kv * 4 + 1], wv.y, s);
                s = fmaf(t[kv * 4 + 2], wv.z, s);
                s = fmaf(t[kv * 4 + 3], wv.w, s);
            }
            out[(size_t)n * DIM + kd] = hp[(size_t)n * DIM + kd] + s;
        }

        float dg = fmaxf(deg[n], 1.0f);
        float inv = __builtin_amdgcn_rcpf(dg);
        float2 po = *reinterpret_cast<const float2*>(pos + (size_t)n * 2);
        float2 pw = *reinterpret_cast<const float2*>(posw + (size_t)n * 2);
        float2 res;
        res.x = po.x + pw.x * inv;
        res.y = po.y + pw.y * inv;
        *reinterpret_cast<float2*>(out + (size_t)N_NODES * DIM + (size_t)n * 2) = res;
    }
}

extern "C" void kernel_launch(void* const* d_in, const int* in_sizes, int n_in,
                              void* d_out, int out_size, void* d_ws, size_t ws_size,
                              hipStream_t stream) {
    const float* h      = (const float*)d_in[0];
    const float* pos    = (const float*)d_in[1];
    const float* h_init = (const float*)d_in[2];
    const float* Wm1    = (const float*)d_in[3];
    const float* bm1    = (const float*)d_in[4];
    const float* Wm2    = (const float*)d_in[5];
    const float* bm2    = (const float*)d_in[6];
    const float* Wp1    = (const float*)d_in[7];
    const float* bp1    = (const float*)d_in[8];
    const float* Wp2    = (const float*)d_in[9];
    const float* bp2    = (const float*)d_in[10];
    const float* Wh1    = (const float*)d_in[11];
    const float* bh1    = (const float*)d_in[12];
    const float* Wh2    = (const float*)d_in[13];
    const float* bh2    = (const float*)d_in[14];
    const void*  eidx   = (const void*)d_in[15];
    float* out = (float*)d_out;

    float* ws   = (float*)d_ws;
    float* hp   = ws;                               // N*64
    float* agg  = ws + (size_t)N_NODES * DIM;       // N*64
    float* posw = agg + (size_t)N_NODES * DIM;      // N*2
    float* deg  = posw + (size_t)N_NODES * 2;       // N
    int*   flag = (int*)(deg + N_NODES);            // 1

    k_init<<<2048, 256, 0, stream>>>(h, h_init, hp, agg, posw, deg, eidx, flag);
    k_edge<<<512, 512, 0, stream>>>(hp, pos, eidx, flag, Wm1, bm1, Wm2, bm2,
                                    Wp1, bp1, Wp2, bp2, agg, posw, deg);
    k_node<<<98, 512, 0, stream>>>(hp, pos, agg, posw, deg, Wh1, bh1, Wh2, bh2, out);
}